// Round 13
// baseline (35.835 us; speedup 1.0000x reference)
//
#include <hip/hip_runtime.h>
#include <math.h>

constexpr int N     = 8192;
constexpr int K     = 30;
constexpr int NBINS = 1024;
constexpr int MB    = 128;      // mrl block size
constexpr int GB    = 256;      // finalize block size
constexpr int GBLK  = N / GB;   // 32 finalize blocks

// d_ws layout (total 61824 B <= 69632 B proven in R1):
//   [0,     32768)  float   mrl[N]
//   [32768, 36864)  uint    incl_cnt[NBINS]   (inclusive count scan)
//   [36864, 45056)  double  incl_sum[NBINS]   (inclusive f64 mrl-sum scan)
//   [45056, 61440)  ushort  sidx[N]           (bin-grouped, index-sorted)
//   [61440, 61696)  double  pnum[GBLK]
//   [61696, 61824)  int     pcnt[GBLK]

// Monotone t->bin map. MUST be the identical expression everywhere.
__device__ __forceinline__ int bin_of(float t) {
    int b = (int)(t * (float)(NBINS / 30.0));
    b = b < 0 ? 0 : b;
    return b > NBINS - 1 ? NBINS - 1 : b;
}

__global__ void mrl_kernel(const float* __restrict__ est,
                           const float* __restrict__ intervals,
                           float* __restrict__ mrl) {
    __shared__ float s_est[MB * K];       // this block's 128 rows, 15 KB

    const int tid  = threadIdx.x;
    const int row0 = blockIdx.x * MB;

    // coalesced staging: 128x30 floats = 1920 float2, 15 per thread
    const float2* src = (const float2*)(est + (size_t)row0 * K);
    float2* dst = (float2*)s_est;
#pragma unroll
    for (int t = 0; t < K / 2; ++t)       // 15
        dst[t * MB + tid] = src[t * MB + tid];
    __syncthreads();

    const float* e = s_est + tid * K;
    double sp = 1.0, m = 0.0;             // f64 accumulation (proven R4/R5)
#pragma unroll
    for (int k = 0; k < K; ++k) {
        float hf = 1.0f / (1.0f + __expf(-e[k]));   // hardware v_exp_f32
        double h = (double)hf;
        m += (double)intervals[k] * h * sp;
        sp *= (1.0 - h);
    }
    mrl[row0 + tid] = (float)m;
}

__global__ void __launch_bounds__(NBINS)
index_kernel(const float* __restrict__ target,
             const float* __restrict__ mrlv,
             unsigned int* __restrict__ g_incl_cnt,
             double* __restrict__ g_incl_sum,
             unsigned short* __restrict__ g_sidx) {
    __shared__ unsigned int   hist[NBINS];   //  4 KB
    __shared__ unsigned int   incl[NBINS];   //  4 KB
    __shared__ unsigned int   fill[NBINS];   //  4 KB
    __shared__ double         dA[NBINS];     //  8 KB
    __shared__ unsigned short sidx[N];       // 16 KB   (36 KB total)

    const int tid = threadIdx.x;             // 0..1023

    hist[tid] = 0u;
    fill[tid] = 0u;
    __syncthreads();

    // 1. histogram (LDS atomics; counts deterministic)
#pragma unroll
    for (int r = 0; r < N / NBINS; ++r) {
        const int i = r * NBINS + tid;
        atomicAdd(&hist[bin_of(target[2 * i])], 1u);
    }
    __syncthreads();

    // 2. inclusive scan of counts (Hillis-Steele, double-sync)
    incl[tid] = hist[tid];
    __syncthreads();
    for (int off = 1; off < NBINS; off <<= 1) {
        const unsigned int add = (tid >= off) ? incl[tid - off] : 0u;
        __syncthreads();
        incl[tid] += add;
        __syncthreads();
    }

    // 3. scatter into bin-grouped slots (slot order nondeterministic -> fixed by step 4)
#pragma unroll
    for (int r = 0; r < N / NBINS; ++r) {
        const int i = r * NBINS + tid;
        const int b = bin_of(target[2 * i]);
        const unsigned int start = (b > 0) ? incl[b - 1] : 0u;
        const unsigned int slot  = atomicAdd(&fill[b], 1u);
        sidx[start + slot] = (unsigned short)i;
    }
    __syncthreads();

    // 4. per-bin: index-sort members (-> deterministic order), then f64 bin sum
    {
        const int b = tid;
        const int s = (b > 0) ? (int)incl[b - 1] : 0;
        const int e = (int)incl[b];
        for (int p = s + 1; p < e; ++p) {            // insertion sort ascending
            const unsigned short v = sidx[p];
            int q = p - 1;
            while (q >= s && sidx[q] > v) { sidx[q + 1] = sidx[q]; --q; }
            sidx[q + 1] = v;
        }
        double bs = 0.0;
        for (int p = s; p < e; ++p)                  // fixed order
            bs += (double)mrlv[sidx[p]];
        dA[b] = bs;
    }
    __syncthreads();

    // 5. inclusive f64 scan of bin sums
    for (int off = 1; off < NBINS; off <<= 1) {
        const double add = (tid >= off) ? dA[tid - off] : 0.0;
        __syncthreads();
        dA[tid] += add;
        __syncthreads();
    }

    // 6. publish
    g_incl_cnt[tid] = incl[tid];
    g_incl_sum[tid] = dA[tid];
#pragma unroll
    for (int r = 0; r < N / NBINS; ++r)
        g_sidx[r * NBINS + tid] = sidx[r * NBINS + tid];
}

__global__ void finalize_kernel(const float* __restrict__ target,
                                const float* __restrict__ mrlv,
                                const unsigned int* __restrict__ incl_cnt,
                                const double* __restrict__ incl_sum,
                                const unsigned short* __restrict__ sidx,
                                double* __restrict__ pnum,
                                int* __restrict__ pcnt) {
    __shared__ double r_num[GB];
    __shared__ int    r_cnt[GB];

    const int tid = threadIdx.x;
    const int i   = blockIdx.x * GB + tid;

    const float2 tv = ((const float2*)target)[i];
    const float  ti = tv.x;
    const bool   ev = (tv.y != 0.0f);
    const float  mi = mrlv[i];

    const int b = bin_of(ti);                        // identical map as index_kernel
    const unsigned int endo   = incl_cnt[b];
    const unsigned int starto = (b > 0) ? incl_cnt[b - 1] : 0u;

    // bins strictly greater than b: all t_j > t_i by monotonicity
    double S = incl_sum[NBINS - 1] - incl_sum[b];
    int    c = N - (int)endo;

    // same-bin members: exact strict compare, fixed (index-sorted) order
    for (unsigned int p = starto; p < endo; ++p) {
        const int   j  = sidx[p];
        const float tj = target[2 * j];
        if (tj > ti) { ++c; S += (double)mrlv[j]; }
    }

    r_num[tid] = ev ? ((double)c * (double)mi - S) : 0.0;
    r_cnt[tid] = ev ? c : 0;
    __syncthreads();
    for (int s = GB / 2; s > 0; s >>= 1) {
        if (tid < s) {
            r_num[tid] += r_num[tid + s];
            r_cnt[tid] += r_cnt[tid + s];
        }
        __syncthreads();
    }
    if (tid == 0) {
        pnum[blockIdx.x] = r_num[0];
        pcnt[blockIdx.x] = r_cnt[0];
    }
}

__global__ void out_kernel(const double* __restrict__ pnum,
                           const int* __restrict__ pcnt,
                           float* __restrict__ out) {
    double n = 0.0;
    double c = 0.0;
#pragma unroll
    for (int p = 0; p < GBLK; ++p) {                 // fixed order
        n += pnum[p];
        c += (double)pcnt[p];
    }
    out[0] = (float)(n / c);
}

extern "C" void kernel_launch(void* const* d_in, const int* in_sizes, int n_in,
                              void* d_out, int out_size, void* d_ws, size_t ws_size,
                              hipStream_t stream) {
    const float* est       = (const float*)d_in[0];   // (N, K) fp32
    const float* target    = (const float*)d_in[1];   // (N, 2) fp32
    const float* intervals = (const float*)d_in[2];   // (K,)  fp32
    float* out = (float*)d_out;

    float*          mrl      = (float*)d_ws;
    unsigned int*   incl_cnt = (unsigned int*)((char*)d_ws + 32768);
    double*         incl_sum = (double*)((char*)d_ws + 36864);
    unsigned short* sidx     = (unsigned short*)((char*)d_ws + 45056);
    double*         pnum     = (double*)((char*)d_ws + 61440);
    int*            pcnt     = (int*)((char*)d_ws + 61696);

    mrl_kernel<<<N / MB, MB, 0, stream>>>(est, intervals, mrl);
    index_kernel<<<1, NBINS, 0, stream>>>(target, mrl, incl_cnt, incl_sum, sidx);
    finalize_kernel<<<GBLK, GB, 0, stream>>>(target, mrl, incl_cnt, incl_sum,
                                             sidx, pnum, pcnt);
    out_kernel<<<1, 1, 0, stream>>>(pnum, pcnt, out);
}